// Round 8
// baseline (184.068 us; speedup 1.0000x reference)
//
#include <hip/hip_runtime.h>
#include <math.h>

#define B_  2
#define T_  2048
#define D_  1024
#define H_  16
#define HS_ 64
#define M_  (B_*T_)   // 4096

typedef __bf16 bf16x8 __attribute__((ext_vector_type(8)));
typedef float  f32x4  __attribute__((ext_vector_type(4)));
typedef unsigned short u16;

// native HW cvt (v_cvt_pk_bf16_f32 when paired) — RNE, 1 inst vs 3-4 manual
static __device__ __forceinline__ u16 f2bf(float f) {
    __bf16 h = (__bf16)f;
    return *reinterpret_cast<u16*>(&h);
}

// async global->LDS, 16B/lane; LDS dest is lane-linear (base + lane*16).
static __device__ __forceinline__ void glds16(const u16* g, u16* l) {
    __builtin_amdgcn_global_load_lds(
        (const __attribute__((address_space(1))) void*)g,
        (__attribute__((address_space(3))) void*)l, 16, 0, 0);
}

// ---------------- fused prep: cast x, transpose+cast both weights ----------
__global__ __launch_bounds__(256) void prep_kernel(
    const float* __restrict__ x, const float* __restrict__ w_qkv,
    const float* __restrict__ w_out,
    u16* __restrict__ Xb, u16* __restrict__ WqkvT, u16* __restrict__ WoutT)
{
    int bid = blockIdx.x;
    if (bid < 4096) {                       // cast x
        int i = (bid * 256 + threadIdx.x) * 4;
        float4 v = *reinterpret_cast<const float4*>(x + i);
        ushort4 o;
        o.x = f2bf(v.x); o.y = f2bf(v.y); o.z = f2bf(v.z); o.w = f2bf(v.w);
        *reinterpret_cast<ushort4*>(Xb + i) = o;
        return;
    }
    const float* in; u16* out; int C; int c0, r0;
    if (bid < 4096 + 3072) {                // w_qkv (D x 3D) -> (3D x D)
        int t = bid - 4096;
        in = w_qkv; out = WqkvT; C = 3 * D_;
        c0 = (t % 96) * 32; r0 = (t / 96) * 32;
    } else {                                // w_out (D x D) -> (D x D)
        int t = bid - 7168;
        in = w_out; out = WoutT; C = D_;
        c0 = (t & 31) * 32; r0 = (t >> 5) * 32;
    }
    __shared__ float tile[32][33];
    int tr = threadIdx.x >> 3, tc4 = (threadIdx.x & 7) * 4;
    float4 v = *reinterpret_cast<const float4*>(in + (size_t)(r0 + tr) * C + c0 + tc4);
    tile[tr][tc4+0] = v.x; tile[tr][tc4+1] = v.y;
    tile[tr][tc4+2] = v.z; tile[tr][tc4+3] = v.w;
    __syncthreads();
    ushort4 o;
    o.x = f2bf(tile[tc4+0][tr]); o.y = f2bf(tile[tc4+1][tr]);
    o.z = f2bf(tile[tc4+2][tr]); o.w = f2bf(tile[tc4+3][tr]);
    *reinterpret_cast<ushort4*>(out + (size_t)(c0 + tr) * D_ + r0 + tc4) = o;
}

// ---------------- QKV GEMM: 4-phase-per-K-tile pipeline (R2) + XCD swizzle -
__global__ __launch_bounds__(512, 2) void gemm_qkv(
    const u16* __restrict__ A, const u16* __restrict__ Bt,
    const float* __restrict__ bias,
    u16* __restrict__ Qb, u16* __restrict__ Kb, u16* __restrict__ Vt)
{
    constexpr int K  = D_;        // 1024
    constexpr int NT = K / 64;    // 16

    __shared__ u16 LDS[2][2][2][8192];  // [buf][A|B][khalf][256r x 32k swz] = 128 KiB

    const int tid  = threadIdx.x;
    const int lane = tid & 63, wave = tid >> 6;
    const int wm = wave >> 2, wn = wave & 3;       // 2 x 4
    const int quad = lane >> 4, lr = lane & 15;

    const int lin = blockIdx.x + 16 * blockIdx.y;  // x-major dispatch order
    const int xcd = lin & 7, rr = lin >> 3;        // rr 0..23
    const int bm = (xcd & 3) * 4 + (rr & 3);
    const int bn = (xcd >> 2) * 6 + (rr >> 2);

    const u16* Ab = A  + (size_t)(bm * 256) * K;
    const u16* Bb = Bt + (size_t)(bn * 256) * K;

    const int r0 = tid >> 2;
    const int c0 = (tid & 3) ^ ((tid >> 3) & 3);
    const u16* sA0 = Ab + (size_t)r0 * K + c0 * 8;
    const u16* sA1 = sA0 + (size_t)128 * K;
    const u16* sB0 = Bb + (size_t)r0 * K + c0 * 8;
    const u16* sB1 = sB0 + (size_t)128 * K;
    const int d0 = tid * 8, d1 = (tid + 512) * 8;

    const int swz = (lr >> 1) & 3;
    const int eA = ((wm*128 + lr) * 4 + (quad ^ swz)) * 8;
    const int eB = ((wn*64  + lr) * 4 + (quad ^ swz)) * 8;

    f32x4 acc[8][4] = {};

#define STG(mat, kh, tt) do { \
        u16* _d = &LDS[(tt) & 1][mat][kh][0]; \
        const int _ko = (tt) * 64 + (kh) * 32; \
        glds16(((mat) ? sB0 : sA0) + _ko, _d + d0); \
        glds16(((mat) ? sB1 : sA1) + _ko, _d + d1); \
    } while (0)

#define MFMA_QUAD(mh) do { \
        __builtin_amdgcn_s_setprio(1); \
        _Pragma("unroll") \
        for (int i_ = 0; i_ < 4; ++i_) \
            _Pragma("unroll") \
            for (int j_ = 0; j_ < 4; ++j_) \
                acc[(mh)*4 + i_][j_] = __builtin_amdgcn_mfma_f32_16x16x32_bf16( \
                    a[i_], b[j_], acc[(mh)*4 + i_][j_], 0, 0, 0); \
        __builtin_amdgcn_s_setprio(0); \
    } while (0)

    STG(0,0,0); STG(1,0,0); STG(0,1,0); STG(1,1,0);
    asm volatile("s_waitcnt vmcnt(4)" ::: "memory");
    __builtin_amdgcn_s_barrier();

    for (int t = 0; t < NT; ++t) {
        const int cb = t & 1;
        const bool last = (t == NT - 1);
        const u16* Ar0 = &LDS[cb][0][0][0];
        const u16* Ar1 = &LDS[cb][0][1][0];
        const u16* Br0 = &LDS[cb][1][0][0];
        const u16* Br1 = &LDS[cb][1][1][0];
        bf16x8 a[4], b[4];

        // ---- phase A: k0, m-frags 0-3 (+ b k0) ----
        #pragma unroll
        for (int i = 0; i < 4; ++i) a[i] = *reinterpret_cast<const bf16x8*>(Ar0 + eA + i*512);
        #pragma unroll
        for (int j = 0; j < 4; ++j) b[j] = *reinterpret_cast<const bf16x8*>(Br0 + eB + j*512);
        if (!last) STG(0,0,t+1);
        __builtin_amdgcn_s_barrier();
        asm volatile("s_waitcnt lgkmcnt(0)" ::: "memory");
        MFMA_QUAD(0);
        __builtin_amdgcn_s_barrier();

        // ---- phase B: k0, m-frags 4-7 (b reused) ----
        #pragma unroll
        for (int i = 0; i < 4; ++i) a[i] = *reinterpret_cast<const bf16x8*>(Ar0 + eA + (i+4)*512);
        if (!last) STG(1,0,t+1);
        __builtin_amdgcn_s_barrier();
        asm volatile("s_waitcnt lgkmcnt(0)" ::: "memory");
        MFMA_QUAD(1);
        if (!last) { asm volatile("s_waitcnt vmcnt(4)" ::: "memory"); }
        else       { asm volatile("s_waitcnt vmcnt(0)" ::: "memory"); }
        __builtin_amdgcn_s_barrier();

        // ---- phase C: k1, m-frags 0-3 (+ b k1) ----
        #pragma unroll
        for (int i = 0; i < 4; ++i) a[i] = *reinterpret_cast<const bf16x8*>(Ar1 + eA + i*512);
        #pragma unroll
        for (int j = 0; j < 4; ++j) b[j] = *reinterpret_cast<const bf16x8*>(Br1 + eB + j*512);
        if (!last) STG(0,1,t+1);
        __builtin_amdgcn_s_barrier();
        asm volatile("s_waitcnt lgkmcnt(0)" ::: "memory");
        MFMA_QUAD(0);
        __builtin_amdgcn_s_barrier();

        // ---- phase D: k1, m-frags 4-7 ----
        #pragma unroll
        for (int i = 0; i < 4; ++i) a[i] = *reinterpret_cast<const bf16x8*>(Ar1 + eA + (i+4)*512);
        if (!last) STG(1,1,t+1);
        __builtin_amdgcn_s_barrier();
        asm volatile("s_waitcnt lgkmcnt(0)" ::: "memory");
        MFMA_QUAD(1);
        asm volatile("s_waitcnt vmcnt(4)" ::: "memory");
        __builtin_amdgcn_s_barrier();
    }
#undef STG
#undef MFMA_QUAD

    // -------- epilogue: scatter to Q (scale folded) / K / V^T --------
    #pragma unroll
    for (int i = 0; i < 8; ++i) {
        int m0 = bm*256 + wm*128 + i*16 + quad*4;   // 4-aligned
        #pragma unroll
        for (int j = 0; j < 4; ++j) {
            int ncol = bn*256 + wn*64 + j*16 + lr;
            float bv = bias[ncol];
            float v4[4];
            #pragma unroll
            for (int r = 0; r < 4; ++r) v4[r] = acc[i][j][r] + bv;
            int bb = m0 >> 11, t0 = m0 & (T_ - 1);
            int s = ncol >> 10, rem = ncol & 1023;
            int h = rem >> 6, d = rem & 63;
            int bh = bb * H_ + h;
            if (s == 0) {
                // fold softmax scale AND log2(e) (attn uses exp2): 0.125*log2e
                #pragma unroll
                for (int r = 0; r < 4; ++r)
                    Qb[((size_t)bh*T_ + t0 + r)*HS_ + d] = f2bf(v4[r] * 0.1803368801111244f);
            } else if (s == 1) {
                #pragma unroll
                for (int r = 0; r < 4; ++r)
                    Kb[((size_t)bh*T_ + t0 + r)*HS_ + d] = f2bf(v4[r]);
            } else {
                ushort4 o;   // consecutive t -> one 8B store
                o.x = f2bf(v4[0]); o.y = f2bf(v4[1]);
                o.z = f2bf(v4[2]); o.w = f2bf(v4[3]);
                *reinterpret_cast<ushort4*>(&Vt[((size_t)bh*HS_ + d)*T_ + t0]) = o;
            }
        }
    }
}

// ---------------- out-proj GEMM: 2-phase-per-K-tile pipeline (R3) ----------
__global__ __launch_bounds__(256, 2) void gemm_out(
    const u16* __restrict__ A, const u16* __restrict__ Bt,
    const float* __restrict__ bias, float* __restrict__ Cf)
{
    constexpr int K  = D_;        // 1024
    constexpr int N  = D_;
    constexpr int NT = K / 64;    // 16

    __shared__ u16 LDS[2][2][2][4096];  // [buf][A|B][khalf][128r x 32k swz] = 64 KiB

    const int tid  = threadIdx.x;
    const int lane = tid & 63, wave = tid >> 6;
    const int wm = wave >> 1, wn = wave & 1;       // 2 x 2
    const int quad = lane >> 4, lr = lane & 15;
    const int bm = blockIdx.x, bn = blockIdx.y;

    const u16* Ab = A  + (size_t)(bm * 128) * K;
    const u16* Bb = Bt + (size_t)(bn * 128) * K;

    const int r0 = tid >> 2;
    const int c0 = (tid & 3) ^ ((tid >> 3) & 3);
    const u16* sA0 = Ab + (size_t)r0 * K + c0 * 8;
    const u16* sA1 = sA0 + (size_t)64 * K;
    const u16* sB0 = Bb + (size_t)r0 * K + c0 * 8;
    const u16* sB1 = sB0 + (size_t)64 * K;
    const int d0 = tid * 8, d1 = (tid + 256) * 8;

    const int swz = (lr >> 1) & 3;
    const int eA = ((wm*64 + lr) * 4 + (quad ^ swz)) * 8;
    const int eB = ((wn*64 + lr) * 4 + (quad ^ swz)) * 8;

    f32x4 acc[4][4] = {};

#define STGO(kh, tt) do { \
        const int _ko = (tt) * 64 + (kh) * 32; \
        glds16(sA0 + _ko, &LDS[(tt) & 1][0][kh][0] + d0); \
        glds16(sA1 + _ko, &LDS[(tt) & 1][0][kh][0] + d1); \
        glds16(sB0 + _ko, &LDS[(tt) & 1][1][kh][0] + d0); \
        glds16(sB1 + _ko, &LDS[(tt) & 1][1][kh][0] + d1); \
    } while (0)

    STGO(0, 0); STGO(1, 0);
    asm volatile("s_waitcnt vmcnt(4)" ::: "memory");
    __builtin_amdgcn_s_barrier();

    for (int t = 0; t < NT; ++t) {
        const int cb = t & 1;
        const bool last = (t == NT - 1);
        bf16x8 a[4], b[4];

        // ---- phase 0: k-half 0 ----
        {
            const u16* Ar = &LDS[cb][0][0][0];
            const u16* Br = &LDS[cb][1][0][0];
            #pragma unroll
            for (int i = 0; i < 4; ++i) a[i] = *reinterpret_cast<const bf16x8*>(Ar + eA + i*512);
            #pragma unroll
            for (int j = 0; j < 4; ++j) b[j] = *reinterpret_cast<const bf16x8*>(Br + eB + j*512);
            if (!last) STGO(0, t+1);
            __builtin_amdgcn_s_barrier();
            asm volatile("s_waitcnt lgkmcnt(0)" ::: "memory");
            __builtin_amdgcn_s_setprio(1);
            #pragma unroll
            for (int i = 0; i < 4; ++i)
                #pragma unroll
                for (int j = 0; j < 4; ++j)
                    acc[i][j] = __builtin_amdgcn_mfma_f32_16x16x32_bf16(a[i], b[j], acc[i][j], 0, 0, 0);
            __builtin_amdgcn_s_setprio(0);
            if (!last) { asm volatile("s_waitcnt vmcnt(4)" ::: "memory"); }
            else       { asm volatile("s_waitcnt vmcnt(0)" ::: "memory"); }
            __builtin_amdgcn_s_barrier();
        }

        // ---- phase 1: k-half 1 ----
        {
            const u16* Ar = &LDS[cb][0][1][0];
            const u16* Br = &LDS[cb][1][1][0];
            #pragma unroll
            for (int i = 0; i < 4; ++i) a[i] = *reinterpret_cast<const bf16x8*>(Ar + eA + i*512);
            #pragma unroll
            for (int j = 0; j < 4; ++j) b[j] = *reinterpret_cast<const bf16x8*>(Br + eB + j*512);
            if (!last) STGO(1, t+1);
            __builtin_amdgcn_s_barrier();
            asm volatile("s_waitcnt lgkmcnt(0)" ::: "memory");
            __builtin_amdgcn_s_setprio(1);
            #pragma unroll
            for (int i = 0; i < 4; ++i)
                #pragma unroll
                for (int j = 0; j < 4; ++j)
                    acc[i][j] = __builtin_amdgcn_mfma_f32_16x16x32_bf16(a[i], b[j], acc[i][j], 0, 0, 0);
            __builtin_amdgcn_s_setprio(0);
            if (!last) { asm volatile("s_waitcnt vmcnt(4)" ::: "memory"); }
            __builtin_amdgcn_s_barrier();
        }
    }
#undef STGO

    #pragma unroll
    for (int i = 0; i < 4; ++i) {
        int m0 = bm*128 + wm*64 + i*16 + quad*4;
        #pragma unroll
        for (int j = 0; j < 4; ++j) {
            int ncol = bn*128 + wn*64 + j*16 + lr;
            float bv = bias[ncol];
            #pragma unroll
            for (int r = 0; r < 4; ++r)
                Cf[(size_t)(m0 + r) * N + ncol] = acc[i][j][r] + bv;
        }
    }
}

// ---------------- Flash attention: PAIRED q-tiles + SPLIT-K halves --------
// 1024 blocks x 256 thr = 4 blocks/CU (2x the waves of R5/R6 — the counters
// said latency-bound at 17% occupancy). Block (bh, p, h): pair (qlo=p,
// qhi=31-p), key-half h. Split point s makes both halves 16/17 work-units
// exactly: s = p<=7 ? 15-p : 8. Softmax here is exp2 WITHOUT running max
// => partial O and partial row-sums are LINEAR: block writes un-normalized
// f32 partials + row sums; merge_kernel computes (O0+O1)/(l0+l1).
// Internals = R5 structure (reg-staged prefetch, 32 KB LDS) — measured
// better than R6's glds-direct variant.
__global__ __launch_bounds__(256) void attn_kernel(
    const u16* __restrict__ Qb, const u16* __restrict__ Kb,
    const u16* __restrict__ Vt, float* __restrict__ Op, float* __restrict__ Lp)
{
    __shared__ u16 Ks[64 * 64];        // [key][d], swizzled chunks, 8 KB
    __shared__ u16 Vs[64 * 64];        // [d][key], swizzled chunks, 8 KB
    __shared__ u16 Ps[4][2][16 * 64];  // per-wave P, [set: lo|hi], 16 KB

    int tid  = threadIdx.x;
    int lane = tid & 63, wave = tid >> 6;          // wave 0..3
    int quad = lane >> 4, lr = lane & 15;

    int lin = blockIdx.x;                          // 1024 blocks
    int bh  = (lin & 7) + 8 * ((lin >> 3) & 3);    // XCD-local bh (4 bh/XCD)
    int rest = lin >> 5;                           // 0..31
    int p   = rest & 15;                           // pair 0..15
    int hB  = rest >> 4;                           // key-half 0|1
    int qlo = p, qhi = 31 - p;
    int s   = (p <= 7) ? (15 - p) : 8;             // balanced split point
    int j0  = hB ? s : 0;
    int j1  = hB ? (qhi + 1) : s;
    int rlo = qlo * 64 + wave * 16;                // wave's 16 q-rows, lo set
    int rhi = qhi * 64 + wave * 16;                // hi set

    // Q fragments (A-layout); 1/sqrt(HS)*log2e pre-folded upstream
    const u16* QpL = Qb + ((size_t)bh * T_ + rlo) * HS_;
    const u16* QpH = Qb + ((size_t)bh * T_ + rhi) * HS_;
    bf16x8 qfL[2], qfH[2];
    #pragma unroll
    for (int h2 = 0; h2 < 2; ++h2) {
        qfL[h2] = *reinterpret_cast<const bf16x8*>(QpL + lr*HS_ + h2*32 + quad*8);
        qfH[h2] = *reinterpret_cast<const bf16x8*>(QpH + lr*HS_ + h2*32 + quad*8);
    }

    f32x4 OaL[4] = {}, OaH[4] = {};
    float lrL[4] = {0.f,0.f,0.f,0.f}, lrH[4] = {0.f,0.f,0.f,0.f};

    // ---- loop-invariant LDS addresses (u16-element offsets) ----
    int e   = quad ^ (lr & 7);
    int rb0 = (lr * 8 + e) * 8;          // kk=0 base (chunk-slot*8 u16)
    int rb1 = (lr * 8 + (e ^ 4)) * 8;    // kk=1 base
    int offw[4][4];
    #pragma unroll
    for (int nt = 0; nt < 4; ++nt)
        #pragma unroll
        for (int r = 0; r < 4; ++r) {
            int prow = quad*4 + r;
            offw[nt][r] = (prow*8 + ((nt*2 + (lr >> 3)) ^ (prow & 7)))*8 + (lr & 7);
        }
    u16* PsL = Ps[wave][0];
    u16* PsH = Ps[wave][1];

    // staging: 256 thr x 2 chunks per matrix; swizzle via source redirect;
    // pointers start at key-tile j0.
    int srow = tid >> 3;
    int scol = ((tid & 7) ^ (srow & 7)) * 8;
    const u16* kp0 = Kb + ((size_t)bh*T_ + j0*64 + srow     )*HS_ + scol;
    const u16* kp1 = Kb + ((size_t)bh*T_ + j0*64 + srow + 32)*HS_ + scol;
    const u16* vp0 = Vt + ((size_t)bh*HS_ + srow     )*T_ + j0*64 + scol;
    const u16* vp1 = Vt + ((size_t)bh*HS_ + srow + 32)*T_ + j0*64 + scol;

    bf16x8 kpre0 = *reinterpret_cast<const bf16x8*>(kp0);
    bf16x8 kpre1 = *reinterpret_cast<const bf16x8*>(kp1);
    bf16x8 vpre0 = *reinterpret_cast<const bf16x8*>(vp0);
    bf16x8 vpre1 = *reinterpret_cast<const bf16x8*>(vp1);

    for (int jt = j0; jt < j1; ++jt) {
        __syncthreads();
        reinterpret_cast<bf16x8*>(Ks)[tid]       = kpre0;
        reinterpret_cast<bf16x8*>(Ks)[tid + 256] = kpre1;
        reinterpret_cast<bf16x8*>(Vs)[tid]       = vpre0;
        reinterpret_cast<bf16x8*>(Vs)[tid + 256] = vpre1;
        if (jt + 1 < j1) {
            kp0 += 64*HS_; kp1 += 64*HS_; vp0 += 64; vp1 += 64;
            kpre0 = *reinterpret_cast<const bf16x8*>(kp0);
            kpre1 = *reinterpret_cast<const bf16x8*>(kp1);
            vpre0 = *reinterpret_cast<const bf16x8*>(vp0);
            vpre1 = *reinterpret_cast<const bf16x8*>(vp1);
        }
        __syncthreads();

        const bool lo = (jt <= qlo);   // wave-uniform

        // S = Q @ K^T for hi set (always) and lo set (while active)
        f32x4 SaH[4] = {}, SaL[4] = {};
        __builtin_amdgcn_s_setprio(1);
        #pragma unroll
        for (int nt = 0; nt < 4; ++nt) {
            bf16x8 bk0 = *reinterpret_cast<const bf16x8*>(Ks + rb0 + nt*1024);
            bf16x8 bk1 = *reinterpret_cast<const bf16x8*>(Ks + rb1 + nt*1024);
            SaH[nt] = __builtin_amdgcn_mfma_f32_16x16x32_bf16(qfH[0], bk0, SaH[nt], 0, 0, 0);
            SaH[nt] = __builtin_amdgcn_mfma_f32_16x16x32_bf16(qfH[1], bk1, SaH[nt], 0, 0, 0);
        }
        if (lo) {
            #pragma unroll
            for (int nt = 0; nt < 4; ++nt) {
                bf16x8 bk0 = *reinterpret_cast<const bf16x8*>(Ks + rb0 + nt*1024);
                bf16x8 bk1 = *reinterpret_cast<const bf16x8*>(Ks + rb1 + nt*1024);
                SaL[nt] = __builtin_amdgcn_mfma_f32_16x16x32_bf16(qfL[0], bk0, SaL[nt], 0, 0, 0);
                SaL[nt] = __builtin_amdgcn_mfma_f32_16x16x32_bf16(qfL[1], bk1, SaL[nt], 0, 0, 0);
            }
        }
        __builtin_amdgcn_s_setprio(0);

        if (jt == qhi) {   // causal mask, hi diagonal tile
            int kb = jt * 64;
            #pragma unroll
            for (int nt = 0; nt < 4; ++nt)
                #pragma unroll
                for (int r = 0; r < 4; ++r) {
                    int kg = kb + nt*16 + lr;
                    int qg = rhi + quad*4 + r;
                    if (kg > qg) SaH[nt][r] = -INFINITY;
                }
        }
        if (jt == qlo) {   // causal mask, lo diagonal tile
            int kb = jt * 64;
            #pragma unroll
            for (int nt = 0; nt < 4; ++nt)
                #pragma unroll
                for (int r = 0; r < 4; ++r) {
                    int kg = kb + nt*16 + lr;
                    int qg = rlo + quad*4 + r;
                    if (kg > qg) SaL[nt][r] = -INFINITY;
                }
        }

        // P = exp2(S); per-lane row sums; P -> LDS
        #pragma unroll
        for (int nt = 0; nt < 4; ++nt)
            #pragma unroll
            for (int r = 0; r < 4; ++r) {
                float pv = __builtin_amdgcn_exp2f(SaH[nt][r]);
                lrH[r] += pv;
                PsH[offw[nt][r]] = f2bf(pv);
            }
        if (lo) {
            #pragma unroll
            for (int nt = 0; nt < 4; ++nt)
                #pragma unroll
                for (int r = 0; r < 4; ++r) {
                    float pv = __builtin_amdgcn_exp2f(SaL[nt][r]);
                    lrL[r] += pv;
                    PsL[offw[nt][r]] = f2bf(pv);
                }
        }

        // O += P @ V  (same-wave LDS ordering via lgkmcnt; no barrier)
        __builtin_amdgcn_s_setprio(1);
        #pragma unroll
        for (int kk = 0; kk < 2; ++kk) {
            int rb = kk ? rb1 : rb0;
            bf16x8 pa = *reinterpret_cast<const bf16x8*>(PsH + rb);
            #pragma unroll
            for (int nt = 0; nt < 4; ++nt) {
                bf16x8 vb = *reinterpret_cast<const bf16x8*>(Vs + rb + nt*1024);
                OaH[nt] = __builtin_amdgcn_mfma_f32_16x16x32_bf16(pa, vb, OaH[nt], 0, 0, 0);
            }
        }
        if (lo) {
            #pragma unroll
            for (int kk = 0; kk < 2; ++kk) {
                int rb = kk ? rb1 : rb0;
                bf16x8 pa = *reinterpret_cast<const bf16x8*>(PsL + rb);
                #pragma unroll
                for (int nt = 0; nt < 4; ++nt) {
                    bf16x8 vb = *reinterpret_cast<const bf16x8*>(Vs + rb + nt*1024);
                    OaL[nt] = __builtin_amdgcn_mfma_f32_16x16x32_bf16(pa, vb, OaL[nt], 0, 0, 0);
                }
            }
        }
        __builtin_amdgcn_s_setprio(0);
    }

    // epilogue: un-normalized f32 partials + per-row partial sums.
    // Op layout [h][bh][T][HS] f32; Lp layout [h][bh][T] f32.
    float* OpB = Op + ((size_t)hB * 32 + bh) * T_ * HS_;
    float* LpB = Lp + ((size_t)hB * 32 + bh) * T_;
    #pragma unroll
    for (int r = 0; r < 4; ++r) {
        float sH = lrH[r], sL = lrL[r];
        #pragma unroll
        for (int off = 8; off >= 1; off >>= 1) {
            sH += __shfl_xor(sH, off, 64);
            sL += __shfl_xor(sL, off, 64);
        }
        int qgH = rhi + quad*4 + r;
        int qgL = rlo + quad*4 + r;
        if (lr == 0) {                 // one lane per quad stores its row
            LpB[qgH] = sH;
            LpB[qgL] = sL;
        }
        #pragma unroll
        for (int nt = 0; nt < 4; ++nt) {
            int d = nt*16 + lr;
            OpB[(size_t)qgH*HS_ + d] = OaH[nt][r];
            OpB[(size_t)qgL*HS_ + d] = OaL[nt][r];
        }
    }
}

// ---------------- merge: Ob = (O0+O1)/(l0+l1), f32->bf16 ------------------
// memory-bound: 32MB+2MB read, 8MB write ~= 7 us.
__global__ __launch_bounds__(256) void merge_kernel(
    const float* __restrict__ Op, const float* __restrict__ Lp,
    u16* __restrict__ Ob)
{
    int idx = blockIdx.x * 256 + threadIdx.x;      // 1,048,576 threads
    int e0  = idx * 4;                             // elem in [32][2048][64]
    int row = e0 >> 6;                             // bh*2048 + q
    int d0  = e0 & 63;
    float4 v0 = *reinterpret_cast<const float4*>(Op + (size_t)e0);
    float4 v1 = *reinterpret_cast<const float4*>(Op + (size_t)e0 + (size_t)32*T_*HS_);
    float inv = 1.f / (Lp[row] + Lp[row + 32*T_]);
    int bh = row >> 11, q = row & 2047;
    int b = bh >> 4, hh = bh & 15;
    ushort4 o;
    o.x = f2bf((v0.x + v1.x) * inv);
    o.y = f2bf((v0.y + v1.y) * inv);
    o.z = f2bf((v0.z + v1.z) * inv);
    o.w = f2bf((v0.w + v1.w) * inv);
    *reinterpret_cast<ushort4*>(Ob + ((size_t)(b*T_ + q))*D_ + hh*HS_ + d0) = o;
}

extern "C" void kernel_launch(void* const* d_in, const int* in_sizes, int n_in,
                              void* d_out, int out_size, void* d_ws, size_t ws_size,
                              hipStream_t stream) {
    (void)in_sizes; (void)n_in; (void)out_size; (void)ws_size;
    const float* x     = (const float*)d_in[0];
    const float* w_qkv = (const float*)d_in[1];
    const float* b_qkv = (const float*)d_in[2];
    const float* w_out = (const float*)d_in[3];
    const float* b_out = (const float*)d_in[4];
    float* out = (float*)d_out;

    char* ws = (char*)d_ws;
    u16* Xb    = (u16*)ws; ws += (size_t)M_ * D_ * 2;
    u16* WqkvT = (u16*)ws; ws += (size_t)3 * D_ * D_ * 2;
    u16* WoutT = (u16*)ws; ws += (size_t)D_ * D_ * 2;
    u16* Qb    = (u16*)ws; ws += (size_t)M_ * D_ * 2;
    u16* Kb    = (u16*)ws; ws += (size_t)M_ * D_ * 2;
    u16* Vt    = (u16*)ws; ws += (size_t)M_ * D_ * 2;
    u16* Ob    = (u16*)ws; ws += (size_t)M_ * D_ * 2;
    float* Op  = (float*)ws; ws += (size_t)2 * M_ * D_ * 4;   // 32 MB partials
    float* Lp  = (float*)ws; ws += (size_t)2 * M_ * 16 * 4;   // row sums

    prep_kernel<<<8192, 256, 0, stream>>>(x, w_qkv, w_out, Xb, WqkvT, WoutT);
    gemm_qkv<<<dim3(16, 12), 512, 0, stream>>>(
        Xb, WqkvT, b_qkv, Qb, Kb, Vt);
    // split-K paired attention: 1024 balanced blocks (4/CU)
    attn_kernel<<<1024, 256, 0, stream>>>(Qb, Kb, Vt, Op, Lp);
    merge_kernel<<<4096, 256, 0, stream>>>(Op, Lp, Ob);
    gemm_out<<<dim3(M_/128, D_/128), 256, 0, stream>>>(Ob, WoutT, b_out, out);
}

// Round 9
// 176.976 us; speedup vs baseline: 1.0401x; 1.0401x over previous
//
#include <hip/hip_runtime.h>
#include <math.h>

#define B_  2
#define T_  2048
#define D_  1024
#define H_  16
#define HS_ 64
#define M_  (B_*T_)   // 4096

typedef __bf16 bf16x8 __attribute__((ext_vector_type(8)));
typedef float  f32x4  __attribute__((ext_vector_type(4)));
typedef unsigned short u16;
typedef unsigned int u32;

// native HW cvt (v_cvt_pk_bf16_f32 when paired) — RNE, 1 inst vs 3-4 manual
static __device__ __forceinline__ u16 f2bf(float f) {
    __bf16 h = (__bf16)f;
    return *reinterpret_cast<u16*>(&h);
}

// async global->LDS, 16B/lane; LDS dest is lane-linear (base + lane*16).
static __device__ __forceinline__ void glds16(const u16* g, u16* l) {
    __builtin_amdgcn_global_load_lds(
        (const __attribute__((address_space(1))) void*)g,
        (__attribute__((address_space(3))) void*)l, 16, 0, 0);
}

// ---------------- fused prep: cast x, transpose+cast both weights ----------
__global__ __launch_bounds__(256) void prep_kernel(
    const float* __restrict__ x, const float* __restrict__ w_qkv,
    const float* __restrict__ w_out,
    u16* __restrict__ Xb, u16* __restrict__ WqkvT, u16* __restrict__ WoutT)
{
    int bid = blockIdx.x;
    if (bid < 4096) {                       // cast x
        int i = (bid * 256 + threadIdx.x) * 4;
        float4 v = *reinterpret_cast<const float4*>(x + i);
        ushort4 o;
        o.x = f2bf(v.x); o.y = f2bf(v.y); o.z = f2bf(v.z); o.w = f2bf(v.w);
        *reinterpret_cast<ushort4*>(Xb + i) = o;
        return;
    }
    const float* in; u16* out; int C; int c0, r0;
    if (bid < 4096 + 3072) {                // w_qkv (D x 3D) -> (3D x D)
        int t = bid - 4096;
        in = w_qkv; out = WqkvT; C = 3 * D_;
        c0 = (t % 96) * 32; r0 = (t / 96) * 32;
    } else {                                // w_out (D x D) -> (D x D)
        int t = bid - 7168;
        in = w_out; out = WoutT; C = D_;
        c0 = (t & 31) * 32; r0 = (t >> 5) * 32;
    }
    __shared__ float tile[32][33];
    int tr = threadIdx.x >> 3, tc4 = (threadIdx.x & 7) * 4;
    float4 v = *reinterpret_cast<const float4*>(in + (size_t)(r0 + tr) * C + c0 + tc4);
    tile[tr][tc4+0] = v.x; tile[tr][tc4+1] = v.y;
    tile[tr][tc4+2] = v.z; tile[tr][tc4+3] = v.w;
    __syncthreads();
    ushort4 o;
    o.x = f2bf(tile[tc4+0][tr]); o.y = f2bf(tile[tc4+1][tr]);
    o.z = f2bf(tile[tc4+2][tr]); o.w = f2bf(tile[tc4+3][tr]);
    *reinterpret_cast<ushort4*>(out + (size_t)(c0 + tr) * D_ + r0 + tc4) = o;
}

// ---------------- QKV GEMM: 4-phase-per-K-tile pipeline (R2) + XCD swizzle -
__global__ __launch_bounds__(512, 2) void gemm_qkv(
    const u16* __restrict__ A, const u16* __restrict__ Bt,
    const float* __restrict__ bias,
    u16* __restrict__ Qb, u16* __restrict__ Kb, u16* __restrict__ Vt)
{
    constexpr int K  = D_;        // 1024
    constexpr int NT = K / 64;    // 16

    __shared__ u16 LDS[2][2][2][8192];  // [buf][A|B][khalf][256r x 32k swz] = 128 KiB

    const int tid  = threadIdx.x;
    const int lane = tid & 63, wave = tid >> 6;
    const int wm = wave >> 2, wn = wave & 3;       // 2 x 4
    const int quad = lane >> 4, lr = lane & 15;

    const int lin = blockIdx.x + 16 * blockIdx.y;  // x-major dispatch order
    const int xcd = lin & 7, rr = lin >> 3;        // rr 0..23
    const int bm = (xcd & 3) * 4 + (rr & 3);
    const int bn = (xcd >> 2) * 6 + (rr >> 2);

    const u16* Ab = A  + (size_t)(bm * 256) * K;
    const u16* Bb = Bt + (size_t)(bn * 256) * K;

    const int r0 = tid >> 2;
    const int c0 = (tid & 3) ^ ((tid >> 3) & 3);
    const u16* sA0 = Ab + (size_t)r0 * K + c0 * 8;
    const u16* sA1 = sA0 + (size_t)128 * K;
    const u16* sB0 = Bb + (size_t)r0 * K + c0 * 8;
    const u16* sB1 = sB0 + (size_t)128 * K;
    const int d0 = tid * 8, d1 = (tid + 512) * 8;

    const int swz = (lr >> 1) & 3;
    const int eA = ((wm*128 + lr) * 4 + (quad ^ swz)) * 8;
    const int eB = ((wn*64  + lr) * 4 + (quad ^ swz)) * 8;

    f32x4 acc[8][4] = {};

#define STG(mat, kh, tt) do { \
        u16* _d = &LDS[(tt) & 1][mat][kh][0]; \
        const int _ko = (tt) * 64 + (kh) * 32; \
        glds16(((mat) ? sB0 : sA0) + _ko, _d + d0); \
        glds16(((mat) ? sB1 : sA1) + _ko, _d + d1); \
    } while (0)

#define MFMA_QUAD(mh) do { \
        __builtin_amdgcn_s_setprio(1); \
        _Pragma("unroll") \
        for (int i_ = 0; i_ < 4; ++i_) \
            _Pragma("unroll") \
            for (int j_ = 0; j_ < 4; ++j_) \
                acc[(mh)*4 + i_][j_] = __builtin_amdgcn_mfma_f32_16x16x32_bf16( \
                    a[i_], b[j_], acc[(mh)*4 + i_][j_], 0, 0, 0); \
        __builtin_amdgcn_s_setprio(0); \
    } while (0)

    STG(0,0,0); STG(1,0,0); STG(0,1,0); STG(1,1,0);
    asm volatile("s_waitcnt vmcnt(4)" ::: "memory");
    __builtin_amdgcn_s_barrier();

    for (int t = 0; t < NT; ++t) {
        const int cb = t & 1;
        const bool last = (t == NT - 1);
        const u16* Ar0 = &LDS[cb][0][0][0];
        const u16* Ar1 = &LDS[cb][0][1][0];
        const u16* Br0 = &LDS[cb][1][0][0];
        const u16* Br1 = &LDS[cb][1][1][0];
        bf16x8 a[4], b[4];

        // ---- phase A: k0, m-frags 0-3 (+ b k0) ----
        #pragma unroll
        for (int i = 0; i < 4; ++i) a[i] = *reinterpret_cast<const bf16x8*>(Ar0 + eA + i*512);
        #pragma unroll
        for (int j = 0; j < 4; ++j) b[j] = *reinterpret_cast<const bf16x8*>(Br0 + eB + j*512);
        if (!last) STG(0,0,t+1);
        __builtin_amdgcn_s_barrier();
        asm volatile("s_waitcnt lgkmcnt(0)" ::: "memory");
        MFMA_QUAD(0);
        __builtin_amdgcn_s_barrier();

        // ---- phase B: k0, m-frags 4-7 (b reused) ----
        #pragma unroll
        for (int i = 0; i < 4; ++i) a[i] = *reinterpret_cast<const bf16x8*>(Ar0 + eA + (i+4)*512);
        if (!last) STG(1,0,t+1);
        __builtin_amdgcn_s_barrier();
        asm volatile("s_waitcnt lgkmcnt(0)" ::: "memory");
        MFMA_QUAD(1);
        if (!last) { asm volatile("s_waitcnt vmcnt(4)" ::: "memory"); }
        else       { asm volatile("s_waitcnt vmcnt(0)" ::: "memory"); }
        __builtin_amdgcn_s_barrier();

        // ---- phase C: k1, m-frags 0-3 (+ b k1) ----
        #pragma unroll
        for (int i = 0; i < 4; ++i) a[i] = *reinterpret_cast<const bf16x8*>(Ar1 + eA + i*512);
        #pragma unroll
        for (int j = 0; j < 4; ++j) b[j] = *reinterpret_cast<const bf16x8*>(Br1 + eB + j*512);
        if (!last) STG(0,1,t+1);
        __builtin_amdgcn_s_barrier();
        asm volatile("s_waitcnt lgkmcnt(0)" ::: "memory");
        MFMA_QUAD(0);
        __builtin_amdgcn_s_barrier();

        // ---- phase D: k1, m-frags 4-7 ----
        #pragma unroll
        for (int i = 0; i < 4; ++i) a[i] = *reinterpret_cast<const bf16x8*>(Ar1 + eA + (i+4)*512);
        if (!last) STG(1,1,t+1);
        __builtin_amdgcn_s_barrier();
        asm volatile("s_waitcnt lgkmcnt(0)" ::: "memory");
        MFMA_QUAD(1);
        asm volatile("s_waitcnt vmcnt(4)" ::: "memory");
        __builtin_amdgcn_s_barrier();
    }
#undef STG
#undef MFMA_QUAD

    // -------- epilogue: scatter to Q (scale folded) / K / V^T --------
    #pragma unroll
    for (int i = 0; i < 8; ++i) {
        int m0 = bm*256 + wm*128 + i*16 + quad*4;   // 4-aligned
        #pragma unroll
        for (int j = 0; j < 4; ++j) {
            int ncol = bn*256 + wn*64 + j*16 + lr;
            float bv = bias[ncol];
            float v4[4];
            #pragma unroll
            for (int r = 0; r < 4; ++r) v4[r] = acc[i][j][r] + bv;
            int bb = m0 >> 11, t0 = m0 & (T_ - 1);
            int s = ncol >> 10, rem = ncol & 1023;
            int h = rem >> 6, d = rem & 63;
            int bh = bb * H_ + h;
            if (s == 0) {
                // fold softmax scale AND log2(e) (attn uses exp2): 0.125*log2e
                #pragma unroll
                for (int r = 0; r < 4; ++r)
                    Qb[((size_t)bh*T_ + t0 + r)*HS_ + d] = f2bf(v4[r] * 0.1803368801111244f);
            } else if (s == 1) {
                #pragma unroll
                for (int r = 0; r < 4; ++r)
                    Kb[((size_t)bh*T_ + t0 + r)*HS_ + d] = f2bf(v4[r]);
            } else {
                ushort4 o;   // consecutive t -> one 8B store
                o.x = f2bf(v4[0]); o.y = f2bf(v4[1]);
                o.z = f2bf(v4[2]); o.w = f2bf(v4[3]);
                *reinterpret_cast<ushort4*>(&Vt[((size_t)bh*HS_ + d)*T_ + t0]) = o;
            }
        }
    }
}

// ---------------- out-proj GEMM: 2-phase-per-K-tile pipeline (R3) ----------
__global__ __launch_bounds__(256, 2) void gemm_out(
    const u16* __restrict__ A, const u16* __restrict__ Bt,
    const float* __restrict__ bias, float* __restrict__ Cf)
{
    constexpr int K  = D_;        // 1024
    constexpr int N  = D_;
    constexpr int NT = K / 64;    // 16

    __shared__ u16 LDS[2][2][2][4096];  // [buf][A|B][khalf][128r x 32k swz] = 64 KiB

    const int tid  = threadIdx.x;
    const int lane = tid & 63, wave = tid >> 6;
    const int wm = wave >> 1, wn = wave & 1;       // 2 x 2
    const int quad = lane >> 4, lr = lane & 15;
    const int bm = blockIdx.x, bn = blockIdx.y;

    const u16* Ab = A  + (size_t)(bm * 128) * K;
    const u16* Bb = Bt + (size_t)(bn * 128) * K;

    const int r0 = tid >> 2;
    const int c0 = (tid & 3) ^ ((tid >> 3) & 3);
    const u16* sA0 = Ab + (size_t)r0 * K + c0 * 8;
    const u16* sA1 = sA0 + (size_t)64 * K;
    const u16* sB0 = Bb + (size_t)r0 * K + c0 * 8;
    const u16* sB1 = sB0 + (size_t)64 * K;
    const int d0 = tid * 8, d1 = (tid + 256) * 8;

    const int swz = (lr >> 1) & 3;
    const int eA = ((wm*64 + lr) * 4 + (quad ^ swz)) * 8;
    const int eB = ((wn*64 + lr) * 4 + (quad ^ swz)) * 8;

    f32x4 acc[4][4] = {};

#define STGO(kh, tt) do { \
        const int _ko = (tt) * 64 + (kh) * 32; \
        glds16(sA0 + _ko, &LDS[(tt) & 1][0][kh][0] + d0); \
        glds16(sA1 + _ko, &LDS[(tt) & 1][0][kh][0] + d1); \
        glds16(sB0 + _ko, &LDS[(tt) & 1][1][kh][0] + d0); \
        glds16(sB1 + _ko, &LDS[(tt) & 1][1][kh][0] + d1); \
    } while (0)

    STGO(0, 0); STGO(1, 0);
    asm volatile("s_waitcnt vmcnt(4)" ::: "memory");
    __builtin_amdgcn_s_barrier();

    for (int t = 0; t < NT; ++t) {
        const int cb = t & 1;
        const bool last = (t == NT - 1);
        bf16x8 a[4], b[4];

        // ---- phase 0: k-half 0 ----
        {
            const u16* Ar = &LDS[cb][0][0][0];
            const u16* Br = &LDS[cb][1][0][0];
            #pragma unroll
            for (int i = 0; i < 4; ++i) a[i] = *reinterpret_cast<const bf16x8*>(Ar + eA + i*512);
            #pragma unroll
            for (int j = 0; j < 4; ++j) b[j] = *reinterpret_cast<const bf16x8*>(Br + eB + j*512);
            if (!last) STGO(0, t+1);
            __builtin_amdgcn_s_barrier();
            asm volatile("s_waitcnt lgkmcnt(0)" ::: "memory");
            __builtin_amdgcn_s_setprio(1);
            #pragma unroll
            for (int i = 0; i < 4; ++i)
                #pragma unroll
                for (int j = 0; j < 4; ++j)
                    acc[i][j] = __builtin_amdgcn_mfma_f32_16x16x32_bf16(a[i], b[j], acc[i][j], 0, 0, 0);
            __builtin_amdgcn_s_setprio(0);
            if (!last) { asm volatile("s_waitcnt vmcnt(4)" ::: "memory"); }
            else       { asm volatile("s_waitcnt vmcnt(0)" ::: "memory"); }
            __builtin_amdgcn_s_barrier();
        }

        // ---- phase 1: k-half 1 ----
        {
            const u16* Ar = &LDS[cb][0][1][0];
            const u16* Br = &LDS[cb][1][1][0];
            #pragma unroll
            for (int i = 0; i < 4; ++i) a[i] = *reinterpret_cast<const bf16x8*>(Ar + eA + i*512);
            #pragma unroll
            for (int j = 0; j < 4; ++j) b[j] = *reinterpret_cast<const bf16x8*>(Br + eB + j*512);
            if (!last) STGO(1, t+1);
            __builtin_amdgcn_s_barrier();
            asm volatile("s_waitcnt lgkmcnt(0)" ::: "memory");
            __builtin_amdgcn_s_setprio(1);
            #pragma unroll
            for (int i = 0; i < 4; ++i)
                #pragma unroll
                for (int j = 0; j < 4; ++j)
                    acc[i][j] = __builtin_amdgcn_mfma_f32_16x16x32_bf16(a[i], b[j], acc[i][j], 0, 0, 0);
            __builtin_amdgcn_s_setprio(0);
            if (!last) { asm volatile("s_waitcnt vmcnt(4)" ::: "memory"); }
            __builtin_amdgcn_s_barrier();
        }
    }
#undef STGO

    #pragma unroll
    for (int i = 0; i < 4; ++i) {
        int m0 = bm*128 + wm*64 + i*16 + quad*4;
        #pragma unroll
        for (int j = 0; j < 4; ++j) {
            int ncol = bn*128 + wn*64 + j*16 + lr;
            float bv = bias[ncol];
            #pragma unroll
            for (int r = 0; r < 4; ++r)
                Cf[(size_t)(m0 + r) * N + ncol] = acc[i][j][r] + bv;
        }
    }
}

// ---------------- Flash attention: PAIRED q-tiles, swapped QK^T (T12) -----
// 512 blocks x 256 thr, R5 staging. This round: instruction diet.
// QK computed as mfma(K, Q) — operand-layout symmetry means BOTH existing
// fragment loads are reused unchanged; output S[key=16nt+4quad+r][q=lr]
// makes each lane's 16 P values share one q-row in contiguous 4-key runs:
//  * P->LDS: 2x v_cvt_pk_bf16_f32 + 1x ds_write_b64 per nt (4 wide writes
//    per set vs 32 scalar b16) into the same chunk-XOR layout the existing
//    rb0/rb1 PA reads consume. <=2-way banks (free).
//  * row-sum: ONE scalar accumulator per set (q=lr lane-local); final
//    reduce = shfl_xor(16)+shfl_xor(32), normalizer via __shfl broadcast.
//  * K and V fragments shared between hi/lo q-sets (one bk/vb read feeds
//    both sets' MFMAs): -16 ds_read_b128 per iteration.
__global__ __launch_bounds__(256) void attn_kernel(
    const u16* __restrict__ Qb, const u16* __restrict__ Kb,
    const u16* __restrict__ Vt, u16* __restrict__ Ob)
{
    __shared__ u16 Ks[64 * 64];        // [key][d], swizzled chunks, 8 KB
    __shared__ u16 Vs[64 * 64];        // [d][key], swizzled chunks, 8 KB
    __shared__ u16 Ps[4][2][16 * 64];  // per-wave P [q][key], [set lo|hi], 16 KB

    int tid  = threadIdx.x;
    int lane = tid & 63, wave = tid >> 6;          // wave 0..3
    int quad = lane >> 4, lr = lane & 15;

    int lin = blockIdx.x;                          // 512 blocks
    int bh  = (lin & 7) + 8 * ((lin >> 3) & 3);    // XCD-local bh (4 bh/XCD)
    int p   = lin >> 5;                            // 0..15
    int qlo = p, qhi = 31 - p;
    int rlo = qlo * 64 + wave * 16;                // wave's 16 q-rows, lo set
    int rhi = qhi * 64 + wave * 16;                // hi set

    // Q fragments — used as the MFMA B operand now (same per-lane data):
    // lane holds Q[q=lr][d=quad*8..+7] (+32 for the second k-half).
    const u16* QpL = Qb + ((size_t)bh * T_ + rlo) * HS_;
    const u16* QpH = Qb + ((size_t)bh * T_ + rhi) * HS_;
    bf16x8 qfL[2], qfH[2];
    #pragma unroll
    for (int h2 = 0; h2 < 2; ++h2) {
        qfL[h2] = *reinterpret_cast<const bf16x8*>(QpL + lr*HS_ + h2*32 + quad*8);
        qfH[h2] = *reinterpret_cast<const bf16x8*>(QpH + lr*HS_ + h2*32 + quad*8);
    }

    f32x4 OaL[4] = {}, OaH[4] = {};
    float lsumL = 0.f, lsumH = 0.f;                // row-sum for q=lr (per set)

    // ---- loop-invariant LDS addresses (u16-element offsets) ----
    int e   = quad ^ (lr & 7);
    int rb0 = (lr * 8 + e) * 8;          // chunk quad of row lr (keys 8q..8q+7)
    int rb1 = (lr * 8 + (e ^ 4)) * 8;    // chunk quad+4 (keys 32+8q..)
    // P b64 write slots: lane(lr,quad,nt) writes keys 16nt+4quad..+3 of row lr
    // -> chunk c=2nt+(quad>>1) at slot lr*8+(c^(lr&7)), byte-offset (quad&1)*8.
    int off64[4];
    #pragma unroll
    for (int nt = 0; nt < 4; ++nt)
        off64[nt] = (lr*8 + ((2*nt + (quad >> 1)) ^ (lr & 7)))*8 + (quad & 1)*4;
    u16* PsL = Ps[wave][0];
    u16* PsH = Ps[wave][1];

    // staging: 256 thr x 2 chunks per matrix; swizzle via source redirect
    int srow = tid >> 3;
    int scol = ((tid & 7) ^ (srow & 7)) * 8;
    const u16* kp0 = Kb + ((size_t)bh*T_ + srow     )*HS_ + scol;
    const u16* kp1 = Kb + ((size_t)bh*T_ + srow + 32)*HS_ + scol;
    const u16* vp0 = Vt + ((size_t)bh*HS_ + srow     )*T_ + scol;
    const u16* vp1 = Vt + ((size_t)bh*HS_ + srow + 32)*T_ + scol;

    bf16x8 kpre0 = *reinterpret_cast<const bf16x8*>(kp0);
    bf16x8 kpre1 = *reinterpret_cast<const bf16x8*>(kp1);
    bf16x8 vpre0 = *reinterpret_cast<const bf16x8*>(vp0);
    bf16x8 vpre1 = *reinterpret_cast<const bf16x8*>(vp1);

    for (int jt = 0; jt <= qhi; ++jt) {
        __syncthreads();
        reinterpret_cast<bf16x8*>(Ks)[tid]       = kpre0;
        reinterpret_cast<bf16x8*>(Ks)[tid + 256] = kpre1;
        reinterpret_cast<bf16x8*>(Vs)[tid]       = vpre0;
        reinterpret_cast<bf16x8*>(Vs)[tid + 256] = vpre1;
        if (jt < qhi) {
            kp0 += 64*HS_; kp1 += 64*HS_; vp0 += 64; vp1 += 64;
            kpre0 = *reinterpret_cast<const bf16x8*>(kp0);
            kpre1 = *reinterpret_cast<const bf16x8*>(kp1);
            vpre0 = *reinterpret_cast<const bf16x8*>(vp0);
            vpre1 = *reinterpret_cast<const bf16x8*>(vp1);
        }
        __syncthreads();

        const bool lo = (jt <= qlo);   // wave-uniform

        // S^T = K @ Q^T: shared K fragments feed both q-sets.
        // Output: Sa[nt][r] = S[key=16nt+4quad+r][q=lr].
        f32x4 SaH[4] = {}, SaL[4] = {};
        __builtin_amdgcn_s_setprio(1);
        #pragma unroll
        for (int nt = 0; nt < 4; ++nt) {
            bf16x8 bk0 = *reinterpret_cast<const bf16x8*>(Ks + rb0 + nt*1024);
            bf16x8 bk1 = *reinterpret_cast<const bf16x8*>(Ks + rb1 + nt*1024);
            SaH[nt] = __builtin_amdgcn_mfma_f32_16x16x32_bf16(bk0, qfH[0], SaH[nt], 0, 0, 0);
            SaH[nt] = __builtin_amdgcn_mfma_f32_16x16x32_bf16(bk1, qfH[1], SaH[nt], 0, 0, 0);
            if (lo) {
                SaL[nt] = __builtin_amdgcn_mfma_f32_16x16x32_bf16(bk0, qfL[0], SaL[nt], 0, 0, 0);
                SaL[nt] = __builtin_amdgcn_mfma_f32_16x16x32_bf16(bk1, qfL[1], SaL[nt], 0, 0, 0);
            }
        }
        __builtin_amdgcn_s_setprio(0);

        if (jt == qhi) {   // causal mask (swapped layout: key index in-regs)
            #pragma unroll
            for (int nt = 0; nt < 4; ++nt)
                #pragma unroll
                for (int r = 0; r < 4; ++r) {
                    int kg = jt*64 + nt*16 + quad*4 + r;
                    int qg = rhi + lr;
                    if (kg > qg) SaH[nt][r] = -INFINITY;
                }
        }
        if (jt == qlo) {
            #pragma unroll
            for (int nt = 0; nt < 4; ++nt)
                #pragma unroll
                for (int r = 0; r < 4; ++r) {
                    int kg = jt*64 + nt*16 + quad*4 + r;
                    int qg = rlo + lr;
                    if (kg > qg) SaL[nt][r] = -INFINITY;
                }
        }

        // P = exp2(S); scalar row-sum; packed b64 writes to [q][key] layout
        #pragma unroll
        for (int nt = 0; nt < 4; ++nt) {
            float e0 = __builtin_amdgcn_exp2f(SaH[nt][0]);
            float e1 = __builtin_amdgcn_exp2f(SaH[nt][1]);
            float e2 = __builtin_amdgcn_exp2f(SaH[nt][2]);
            float e3 = __builtin_amdgcn_exp2f(SaH[nt][3]);
            lsumH += (e0 + e1) + (e2 + e3);
            u32 d0, d1;
            asm("v_cvt_pk_bf16_f32 %0, %1, %2" : "=v"(d0) : "v"(e0), "v"(e1));
            asm("v_cvt_pk_bf16_f32 %0, %1, %2" : "=v"(d1) : "v"(e2), "v"(e3));
            uint2 w; w.x = d0; w.y = d1;
            *reinterpret_cast<uint2*>(PsH + off64[nt]) = w;
        }
        if (lo) {
            #pragma unroll
            for (int nt = 0; nt < 4; ++nt) {
                float e0 = __builtin_amdgcn_exp2f(SaL[nt][0]);
                float e1 = __builtin_amdgcn_exp2f(SaL[nt][1]);
                float e2 = __builtin_amdgcn_exp2f(SaL[nt][2]);
                float e3 = __builtin_amdgcn_exp2f(SaL[nt][3]);
                lsumL += (e0 + e1) + (e2 + e3);
                u32 d0, d1;
                asm("v_cvt_pk_bf16_f32 %0, %1, %2" : "=v"(d0) : "v"(e0), "v"(e1));
                asm("v_cvt_pk_bf16_f32 %0, %1, %2" : "=v"(d1) : "v"(e2), "v"(e3));
                uint2 w; w.x = d0; w.y = d1;
                *reinterpret_cast<uint2*>(PsL + off64[nt]) = w;
            }
        }

        // O += P @ V: shared V fragments feed both q-sets.
        // (same-wave LDS write->read ordering via lgkmcnt; no barrier)
        __builtin_amdgcn_s_setprio(1);
        #pragma unroll
        for (int kk = 0; kk < 2; ++kk) {
            int rb = kk ? rb1 : rb0;
            bf16x8 paH = *reinterpret_cast<const bf16x8*>(PsH + rb);
            bf16x8 paL = *reinterpret_cast<const bf16x8*>(PsL + rb);
            #pragma unroll
            for (int nt = 0; nt < 4; ++nt) {
                bf16x8 vb = *reinterpret_cast<const bf16x8*>(Vs + rb + nt*1024);
                OaH[nt] = __builtin_amdgcn_mfma_f32_16x16x32_bf16(paH, vb, OaH[nt], 0, 0, 0);
                if (lo)
                    OaL[nt] = __builtin_amdgcn_mfma_f32_16x16x32_bf16(paL, vb, OaL[nt], 0, 0, 0);
            }
        }
        __builtin_amdgcn_s_setprio(0);
    }

    // epilogue: full row sums (reduce across quads), normalize, store.
    // lsum holds q=lr's partial; O rows are q=quad*4+r -> broadcast via shfl.
    int b = bh >> 4, h = bh & 15;
    float sH = lsumH;
    sH += __shfl_xor(sH, 16, 64);
    sH += __shfl_xor(sH, 32, 64);
    float sL = lsumL;
    sL += __shfl_xor(sL, 16, 64);
    sL += __shfl_xor(sL, 32, 64);
    #pragma unroll
    for (int r = 0; r < 4; ++r) {
        float invH = 1.f / __shfl(sH, quad*4 + r, 64);
        float invL = 1.f / __shfl(sL, quad*4 + r, 64);
        int qgH = rhi + quad*4 + r;
        int qgL = rlo + quad*4 + r;
        #pragma unroll
        for (int nt = 0; nt < 4; ++nt) {
            int d = nt*16 + lr;
            Ob[((size_t)b*T_ + qgH)*D_ + h*HS_ + d] = f2bf(OaH[nt][r] * invH);
            Ob[((size_t)b*T_ + qgL)*D_ + h*HS_ + d] = f2bf(OaL[nt][r] * invL);
        }
    }
}

extern "C" void kernel_launch(void* const* d_in, const int* in_sizes, int n_in,
                              void* d_out, int out_size, void* d_ws, size_t ws_size,
                              hipStream_t stream) {
    (void)in_sizes; (void)n_in; (void)out_size; (void)ws_size;
    const float* x     = (const float*)d_in[0];
    const float* w_qkv = (const float*)d_in[1];
    const float* b_qkv = (const float*)d_in[2];
    const float* w_out = (const float*)d_in[3];
    const float* b_out = (const float*)d_in[4];
    float* out = (float*)d_out;

    char* ws = (char*)d_ws;
    u16* Xb    = (u16*)ws; ws += (size_t)M_ * D_ * 2;
    u16* WqkvT = (u16*)ws; ws += (size_t)3 * D_ * D_ * 2;
    u16* WoutT = (u16*)ws; ws += (size_t)D_ * D_ * 2;
    u16* Qb    = (u16*)ws; ws += (size_t)M_ * D_ * 2;
    u16* Kb    = (u16*)ws; ws += (size_t)M_ * D_ * 2;
    u16* Vt    = (u16*)ws; ws += (size_t)M_ * D_ * 2;
    u16* Ob    = (u16*)ws; ws += (size_t)M_ * D_ * 2;

    prep_kernel<<<8192, 256, 0, stream>>>(x, w_qkv, w_out, Xb, WqkvT, WoutT);
    gemm_qkv<<<dim3(16, 12), 512, 0, stream>>>(
        Xb, WqkvT, b_qkv, Qb, Kb, Vt);
    // paired q-tiles, swapped-QK in-register-row softmax: 512 blocks
    attn_kernel<<<512, 256, 0, stream>>>(Qb, Kb, Vt, Ob);
    gemm_out<<<dim3(M_/128, D_/128), 256, 0, stream>>>(Ob, WoutT, b_out, out);
}

// Round 10
// 176.235 us; speedup vs baseline: 1.0444x; 1.0042x over previous
//
#include <hip/hip_runtime.h>
#include <math.h>

#define B_  2
#define T_  2048
#define D_  1024
#define H_  16
#define HS_ 64
#define M_  (B_*T_)   // 4096

typedef __bf16 bf16x8 __attribute__((ext_vector_type(8)));
typedef float  f32x4  __attribute__((ext_vector_type(4)));
typedef unsigned short u16;

// native HW cvt (v_cvt_pk_bf16_f32 when paired) — RNE, 1 inst vs 3-4 manual
static __device__ __forceinline__ u16 f2bf(float f) {
    __bf16 h = (__bf16)f;
    return *reinterpret_cast<u16*>(&h);
}

// async global->LDS, 16B/lane; LDS dest is lane-linear (base + lane*16).
static __device__ __forceinline__ void glds16(const u16* g, u16* l) {
    __builtin_amdgcn_global_load_lds(
        (const __attribute__((address_space(1))) void*)g,
        (__attribute__((address_space(3))) void*)l, 16, 0, 0);
}

// ---------------- fused prep: cast x, transpose+cast both weights ----------
__global__ __launch_bounds__(256) void prep_kernel(
    const float* __restrict__ x, const float* __restrict__ w_qkv,
    const float* __restrict__ w_out,
    u16* __restrict__ Xb, u16* __restrict__ WqkvT, u16* __restrict__ WoutT)
{
    int bid = blockIdx.x;
    if (bid < 4096) {                       // cast x
        int i = (bid * 256 + threadIdx.x) * 4;
        float4 v = *reinterpret_cast<const float4*>(x + i);
        ushort4 o;
        o.x = f2bf(v.x); o.y = f2bf(v.y); o.z = f2bf(v.z); o.w = f2bf(v.w);
        *reinterpret_cast<ushort4*>(Xb + i) = o;
        return;
    }
    const float* in; u16* out; int C; int c0, r0;
    if (bid < 4096 + 3072) {                // w_qkv (D x 3D) -> (3D x D)
        int t = bid - 4096;
        in = w_qkv; out = WqkvT; C = 3 * D_;
        c0 = (t % 96) * 32; r0 = (t / 96) * 32;
    } else {                                // w_out (D x D) -> (D x D)
        int t = bid - 7168;
        in = w_out; out = WoutT; C = D_;
        c0 = (t & 31) * 32; r0 = (t >> 5) * 32;
    }
    __shared__ float tile[32][33];
    int tr = threadIdx.x >> 3, tc4 = (threadIdx.x & 7) * 4;
    float4 v = *reinterpret_cast<const float4*>(in + (size_t)(r0 + tr) * C + c0 + tc4);
    tile[tr][tc4+0] = v.x; tile[tr][tc4+1] = v.y;
    tile[tr][tc4+2] = v.z; tile[tr][tc4+3] = v.w;
    __syncthreads();
    ushort4 o;
    o.x = f2bf(tile[tc4+0][tr]); o.y = f2bf(tile[tc4+1][tr]);
    o.z = f2bf(tile[tc4+2][tr]); o.w = f2bf(tile[tc4+3][tr]);
    *reinterpret_cast<ushort4*>(out + (size_t)(c0 + tr) * D_ + r0 + tc4) = o;
}

// ---------------- QKV GEMM: 4-phase-per-K-tile pipeline (R2) + XCD swizzle -
__global__ __launch_bounds__(512, 2) void gemm_qkv(
    const u16* __restrict__ A, const u16* __restrict__ Bt,
    const float* __restrict__ bias,
    u16* __restrict__ Qb, u16* __restrict__ Kb, u16* __restrict__ Vt)
{
    constexpr int K  = D_;        // 1024
    constexpr int NT = K / 64;    // 16

    __shared__ u16 LDS[2][2][2][8192];  // [buf][A|B][khalf][256r x 32k swz] = 128 KiB

    const int tid  = threadIdx.x;
    const int lane = tid & 63, wave = tid >> 6;
    const int wm = wave >> 2, wn = wave & 3;       // 2 x 4
    const int quad = lane >> 4, lr = lane & 15;

    const int lin = blockIdx.x + 16 * blockIdx.y;  // x-major dispatch order
    const int xcd = lin & 7, rr = lin >> 3;        // rr 0..23
    const int bm = (xcd & 3) * 4 + (rr & 3);
    const int bn = (xcd >> 2) * 6 + (rr >> 2);

    const u16* Ab = A  + (size_t)(bm * 256) * K;
    const u16* Bb = Bt + (size_t)(bn * 256) * K;

    const int r0 = tid >> 2;
    const int c0 = (tid & 3) ^ ((tid >> 3) & 3);
    const u16* sA0 = Ab + (size_t)r0 * K + c0 * 8;
    const u16* sA1 = sA0 + (size_t)128 * K;
    const u16* sB0 = Bb + (size_t)r0 * K + c0 * 8;
    const u16* sB1 = sB0 + (size_t)128 * K;
    const int d0 = tid * 8, d1 = (tid + 512) * 8;

    const int swz = (lr >> 1) & 3;
    const int eA = ((wm*128 + lr) * 4 + (quad ^ swz)) * 8;
    const int eB = ((wn*64  + lr) * 4 + (quad ^ swz)) * 8;

    f32x4 acc[8][4] = {};

#define STG(mat, kh, tt) do { \
        u16* _d = &LDS[(tt) & 1][mat][kh][0]; \
        const int _ko = (tt) * 64 + (kh) * 32; \
        glds16(((mat) ? sB0 : sA0) + _ko, _d + d0); \
        glds16(((mat) ? sB1 : sA1) + _ko, _d + d1); \
    } while (0)

#define MFMA_QUAD(mh) do { \
        __builtin_amdgcn_s_setprio(1); \
        _Pragma("unroll") \
        for (int i_ = 0; i_ < 4; ++i_) \
            _Pragma("unroll") \
            for (int j_ = 0; j_ < 4; ++j_) \
                acc[(mh)*4 + i_][j_] = __builtin_amdgcn_mfma_f32_16x16x32_bf16( \
                    a[i_], b[j_], acc[(mh)*4 + i_][j_], 0, 0, 0); \
        __builtin_amdgcn_s_setprio(0); \
    } while (0)

    STG(0,0,0); STG(1,0,0); STG(0,1,0); STG(1,1,0);
    asm volatile("s_waitcnt vmcnt(4)" ::: "memory");
    __builtin_amdgcn_s_barrier();

    for (int t = 0; t < NT; ++t) {
        const int cb = t & 1;
        const bool last = (t == NT - 1);
        const u16* Ar0 = &LDS[cb][0][0][0];
        const u16* Ar1 = &LDS[cb][0][1][0];
        const u16* Br0 = &LDS[cb][1][0][0];
        const u16* Br1 = &LDS[cb][1][1][0];
        bf16x8 a[4], b[4];

        // ---- phase A: k0, m-frags 0-3 (+ b k0) ----
        #pragma unroll
        for (int i = 0; i < 4; ++i) a[i] = *reinterpret_cast<const bf16x8*>(Ar0 + eA + i*512);
        #pragma unroll
        for (int j = 0; j < 4; ++j) b[j] = *reinterpret_cast<const bf16x8*>(Br0 + eB + j*512);
        if (!last) STG(0,0,t+1);
        __builtin_amdgcn_s_barrier();
        asm volatile("s_waitcnt lgkmcnt(0)" ::: "memory");
        MFMA_QUAD(0);
        __builtin_amdgcn_s_barrier();

        // ---- phase B: k0, m-frags 4-7 (b reused) ----
        #pragma unroll
        for (int i = 0; i < 4; ++i) a[i] = *reinterpret_cast<const bf16x8*>(Ar0 + eA + (i+4)*512);
        if (!last) STG(1,0,t+1);
        __builtin_amdgcn_s_barrier();
        asm volatile("s_waitcnt lgkmcnt(0)" ::: "memory");
        MFMA_QUAD(1);
        if (!last) { asm volatile("s_waitcnt vmcnt(4)" ::: "memory"); }
        else       { asm volatile("s_waitcnt vmcnt(0)" ::: "memory"); }
        __builtin_amdgcn_s_barrier();

        // ---- phase C: k1, m-frags 0-3 (+ b k1) ----
        #pragma unroll
        for (int i = 0; i < 4; ++i) a[i] = *reinterpret_cast<const bf16x8*>(Ar1 + eA + i*512);
        #pragma unroll
        for (int j = 0; j < 4; ++j) b[j] = *reinterpret_cast<const bf16x8*>(Br1 + eB + j*512);
        if (!last) STG(0,1,t+1);
        __builtin_amdgcn_s_barrier();
        asm volatile("s_waitcnt lgkmcnt(0)" ::: "memory");
        MFMA_QUAD(0);
        __builtin_amdgcn_s_barrier();

        // ---- phase D: k1, m-frags 4-7 ----
        #pragma unroll
        for (int i = 0; i < 4; ++i) a[i] = *reinterpret_cast<const bf16x8*>(Ar1 + eA + (i+4)*512);
        if (!last) STG(1,1,t+1);
        __builtin_amdgcn_s_barrier();
        asm volatile("s_waitcnt lgkmcnt(0)" ::: "memory");
        MFMA_QUAD(1);
        asm volatile("s_waitcnt vmcnt(4)" ::: "memory");
        __builtin_amdgcn_s_barrier();
    }
#undef STG
#undef MFMA_QUAD

    // -------- epilogue: scatter to Q (scale folded) / K / V^T --------
    #pragma unroll
    for (int i = 0; i < 8; ++i) {
        int m0 = bm*256 + wm*128 + i*16 + quad*4;   // 4-aligned
        #pragma unroll
        for (int j = 0; j < 4; ++j) {
            int ncol = bn*256 + wn*64 + j*16 + lr;
            float bv = bias[ncol];
            float v4[4];
            #pragma unroll
            for (int r = 0; r < 4; ++r) v4[r] = acc[i][j][r] + bv;
            int bb = m0 >> 11, t0 = m0 & (T_ - 1);
            int s = ncol >> 10, rem = ncol & 1023;
            int h = rem >> 6, d = rem & 63;
            int bh = bb * H_ + h;
            if (s == 0) {
                // fold softmax scale AND log2(e) (attn uses exp2): 0.125*log2e
                #pragma unroll
                for (int r = 0; r < 4; ++r)
                    Qb[((size_t)bh*T_ + t0 + r)*HS_ + d] = f2bf(v4[r] * 0.1803368801111244f);
            } else if (s == 1) {
                #pragma unroll
                for (int r = 0; r < 4; ++r)
                    Kb[((size_t)bh*T_ + t0 + r)*HS_ + d] = f2bf(v4[r]);
            } else {
                ushort4 o;   // consecutive t -> one 8B store
                o.x = f2bf(v4[0]); o.y = f2bf(v4[1]);
                o.z = f2bf(v4[2]); o.w = f2bf(v4[3]);
                *reinterpret_cast<ushort4*>(&Vt[((size_t)bh*HS_ + d)*T_ + t0]) = o;
            }
        }
    }
}

// ---------------- out-proj GEMM: 2-phase-per-K-tile pipeline (R3) ----------
__global__ __launch_bounds__(256, 2) void gemm_out(
    const u16* __restrict__ A, const u16* __restrict__ Bt,
    const float* __restrict__ bias, float* __restrict__ Cf)
{
    constexpr int K  = D_;        // 1024
    constexpr int N  = D_;
    constexpr int NT = K / 64;    // 16

    __shared__ u16 LDS[2][2][2][4096];  // [buf][A|B][khalf][128r x 32k swz] = 64 KiB

    const int tid  = threadIdx.x;
    const int lane = tid & 63, wave = tid >> 6;
    const int wm = wave >> 1, wn = wave & 1;       // 2 x 2
    const int quad = lane >> 4, lr = lane & 15;
    const int bm = blockIdx.x, bn = blockIdx.y;

    const u16* Ab = A  + (size_t)(bm * 128) * K;
    const u16* Bb = Bt + (size_t)(bn * 128) * K;

    const int r0 = tid >> 2;
    const int c0 = (tid & 3) ^ ((tid >> 3) & 3);
    const u16* sA0 = Ab + (size_t)r0 * K + c0 * 8;
    const u16* sA1 = sA0 + (size_t)64 * K;
    const u16* sB0 = Bb + (size_t)r0 * K + c0 * 8;
    const u16* sB1 = sB0 + (size_t)64 * K;
    const int d0 = tid * 8, d1 = (tid + 256) * 8;

    const int swz = (lr >> 1) & 3;
    const int eA = ((wm*64 + lr) * 4 + (quad ^ swz)) * 8;
    const int eB = ((wn*64 + lr) * 4 + (quad ^ swz)) * 8;

    f32x4 acc[4][4] = {};

#define STGO(kh, tt) do { \
        const int _ko = (tt) * 64 + (kh) * 32; \
        glds16(sA0 + _ko, &LDS[(tt) & 1][0][kh][0] + d0); \
        glds16(sA1 + _ko, &LDS[(tt) & 1][0][kh][0] + d1); \
        glds16(sB0 + _ko, &LDS[(tt) & 1][1][kh][0] + d0); \
        glds16(sB1 + _ko, &LDS[(tt) & 1][1][kh][0] + d1); \
    } while (0)

    STGO(0, 0); STGO(1, 0);
    asm volatile("s_waitcnt vmcnt(4)" ::: "memory");
    __builtin_amdgcn_s_barrier();

    for (int t = 0; t < NT; ++t) {
        const int cb = t & 1;
        const bool last = (t == NT - 1);
        bf16x8 a[4], b[4];

        // ---- phase 0: k-half 0 ----
        {
            const u16* Ar = &LDS[cb][0][0][0];
            const u16* Br = &LDS[cb][1][0][0];
            #pragma unroll
            for (int i = 0; i < 4; ++i) a[i] = *reinterpret_cast<const bf16x8*>(Ar + eA + i*512);
            #pragma unroll
            for (int j = 0; j < 4; ++j) b[j] = *reinterpret_cast<const bf16x8*>(Br + eB + j*512);
            if (!last) STGO(0, t+1);
            __builtin_amdgcn_s_barrier();
            asm volatile("s_waitcnt lgkmcnt(0)" ::: "memory");
            __builtin_amdgcn_s_setprio(1);
            #pragma unroll
            for (int i = 0; i < 4; ++i)
                #pragma unroll
                for (int j = 0; j < 4; ++j)
                    acc[i][j] = __builtin_amdgcn_mfma_f32_16x16x32_bf16(a[i], b[j], acc[i][j], 0, 0, 0);
            __builtin_amdgcn_s_setprio(0);
            if (!last) { asm volatile("s_waitcnt vmcnt(4)" ::: "memory"); }
            else       { asm volatile("s_waitcnt vmcnt(0)" ::: "memory"); }
            __builtin_amdgcn_s_barrier();
        }

        // ---- phase 1: k-half 1 ----
        {
            const u16* Ar = &LDS[cb][0][1][0];
            const u16* Br = &LDS[cb][1][1][0];
            #pragma unroll
            for (int i = 0; i < 4; ++i) a[i] = *reinterpret_cast<const bf16x8*>(Ar + eA + i*512);
            #pragma unroll
            for (int j = 0; j < 4; ++j) b[j] = *reinterpret_cast<const bf16x8*>(Br + eB + j*512);
            if (!last) STGO(1, t+1);
            __builtin_amdgcn_s_barrier();
            asm volatile("s_waitcnt lgkmcnt(0)" ::: "memory");
            __builtin_amdgcn_s_setprio(1);
            #pragma unroll
            for (int i = 0; i < 4; ++i)
                #pragma unroll
                for (int j = 0; j < 4; ++j)
                    acc[i][j] = __builtin_amdgcn_mfma_f32_16x16x32_bf16(a[i], b[j], acc[i][j], 0, 0, 0);
            __builtin_amdgcn_s_setprio(0);
            if (!last) { asm volatile("s_waitcnt vmcnt(4)" ::: "memory"); }
            __builtin_amdgcn_s_barrier();
        }
    }
#undef STGO

    #pragma unroll
    for (int i = 0; i < 4; ++i) {
        int m0 = bm*128 + wm*64 + i*16 + quad*4;
        #pragma unroll
        for (int j = 0; j < 4; ++j) {
            int ncol = bn*128 + wn*64 + j*16 + lr;
            float bv = bias[ncol];
            #pragma unroll
            for (int r = 0; r < 4; ++r)
                Cf[(size_t)(m0 + r) * N + ncol] = acc[i][j][r] + bv;
        }
    }
}

// ---------------- Flash attention: PAIRED q-tiles, swapped QK^T -----------
// R9 structure (swapped mfma(K,Q), shared K/V fragments between q-sets,
// scalar per-lane row-sum, packed b64 P-writes) with R9's regression fixed:
// NO inline-asm cvt_pk (m240: -37% — compiler emits v_cvt_pk_bf16_f32 from
// paired scalar casts). LDS bytes/wave-iter: 48KB (R5) -> 28KB.
__global__ __launch_bounds__(256) void attn_kernel(
    const u16* __restrict__ Qb, const u16* __restrict__ Kb,
    const u16* __restrict__ Vt, u16* __restrict__ Ob)
{
    __shared__ u16 Ks[64 * 64];        // [key][d], swizzled chunks, 8 KB
    __shared__ u16 Vs[64 * 64];        // [d][key], swizzled chunks, 8 KB
    __shared__ u16 Ps[4][2][16 * 64];  // per-wave P [q][key], [set lo|hi], 16 KB

    int tid  = threadIdx.x;
    int lane = tid & 63, wave = tid >> 6;          // wave 0..3
    int quad = lane >> 4, lr = lane & 15;

    int lin = blockIdx.x;                          // 512 blocks
    int bh  = (lin & 7) + 8 * ((lin >> 3) & 3);    // XCD-local bh (4 bh/XCD)
    int p   = lin >> 5;                            // 0..15
    int qlo = p, qhi = 31 - p;
    int rlo = qlo * 64 + wave * 16;                // wave's 16 q-rows, lo set
    int rhi = qhi * 64 + wave * 16;                // hi set

    // Q fragments — MFMA B operand (same per-lane data as A-layout):
    // lane holds Q[q=lr][d=quad*8..+7] (+32 for the second k-half).
    const u16* QpL = Qb + ((size_t)bh * T_ + rlo) * HS_;
    const u16* QpH = Qb + ((size_t)bh * T_ + rhi) * HS_;
    bf16x8 qfL[2], qfH[2];
    #pragma unroll
    for (int h2 = 0; h2 < 2; ++h2) {
        qfL[h2] = *reinterpret_cast<const bf16x8*>(QpL + lr*HS_ + h2*32 + quad*8);
        qfH[h2] = *reinterpret_cast<const bf16x8*>(QpH + lr*HS_ + h2*32 + quad*8);
    }

    f32x4 OaL[4] = {}, OaH[4] = {};
    float lsumL = 0.f, lsumH = 0.f;                // row-sum for q=lr (per set)

    // ---- loop-invariant LDS addresses (u16-element offsets) ----
    int e   = quad ^ (lr & 7);
    int rb0 = (lr * 8 + e) * 8;          // chunk quad of row lr (keys 8q..8q+7)
    int rb1 = (lr * 8 + (e ^ 4)) * 8;    // chunk quad+4 (keys 32+8q..)
    // P b64 write slots: lane(lr,quad,nt) writes keys 16nt+4quad..+3 of row lr
    // -> chunk c=2nt+(quad>>1) at slot lr*8+(c^(lr&7)), elem-offset (quad&1)*4.
    int off64[4];
    #pragma unroll
    for (int nt = 0; nt < 4; ++nt)
        off64[nt] = (lr*8 + ((2*nt + (quad >> 1)) ^ (lr & 7)))*8 + (quad & 1)*4;
    u16* PsL = Ps[wave][0];
    u16* PsH = Ps[wave][1];

    // staging: 256 thr x 2 chunks per matrix; swizzle via source redirect
    int srow = tid >> 3;
    int scol = ((tid & 7) ^ (srow & 7)) * 8;
    const u16* kp0 = Kb + ((size_t)bh*T_ + srow     )*HS_ + scol;
    const u16* kp1 = Kb + ((size_t)bh*T_ + srow + 32)*HS_ + scol;
    const u16* vp0 = Vt + ((size_t)bh*HS_ + srow     )*T_ + scol;
    const u16* vp1 = Vt + ((size_t)bh*HS_ + srow + 32)*T_ + scol;

    bf16x8 kpre0 = *reinterpret_cast<const bf16x8*>(kp0);
    bf16x8 kpre1 = *reinterpret_cast<const bf16x8*>(kp1);
    bf16x8 vpre0 = *reinterpret_cast<const bf16x8*>(vp0);
    bf16x8 vpre1 = *reinterpret_cast<const bf16x8*>(vp1);

    for (int jt = 0; jt <= qhi; ++jt) {
        __syncthreads();
        reinterpret_cast<bf16x8*>(Ks)[tid]       = kpre0;
        reinterpret_cast<bf16x8*>(Ks)[tid + 256] = kpre1;
        reinterpret_cast<bf16x8*>(Vs)[tid]       = vpre0;
        reinterpret_cast<bf16x8*>(Vs)[tid + 256] = vpre1;
        if (jt < qhi) {
            kp0 += 64*HS_; kp1 += 64*HS_; vp0 += 64; vp1 += 64;
            kpre0 = *reinterpret_cast<const bf16x8*>(kp0);
            kpre1 = *reinterpret_cast<const bf16x8*>(kp1);
            vpre0 = *reinterpret_cast<const bf16x8*>(vp0);
            vpre1 = *reinterpret_cast<const bf16x8*>(vp1);
        }
        __syncthreads();

        const bool lo = (jt <= qlo);   // wave-uniform

        // S^T = K @ Q^T: shared K fragments feed both q-sets.
        // Output: Sa[nt][r] = S[key=16nt+4quad+r][q=lr].
        f32x4 SaH[4] = {}, SaL[4] = {};
        __builtin_amdgcn_s_setprio(1);
        #pragma unroll
        for (int nt = 0; nt < 4; ++nt) {
            bf16x8 bk0 = *reinterpret_cast<const bf16x8*>(Ks + rb0 + nt*1024);
            bf16x8 bk1 = *reinterpret_cast<const bf16x8*>(Ks + rb1 + nt*1024);
            SaH[nt] = __builtin_amdgcn_mfma_f32_16x16x32_bf16(bk0, qfH[0], SaH[nt], 0, 0, 0);
            SaH[nt] = __builtin_amdgcn_mfma_f32_16x16x32_bf16(bk1, qfH[1], SaH[nt], 0, 0, 0);
            if (lo) {
                SaL[nt] = __builtin_amdgcn_mfma_f32_16x16x32_bf16(bk0, qfL[0], SaL[nt], 0, 0, 0);
                SaL[nt] = __builtin_amdgcn_mfma_f32_16x16x32_bf16(bk1, qfL[1], SaL[nt], 0, 0, 0);
            }
        }
        __builtin_amdgcn_s_setprio(0);

        if (jt == qhi) {   // causal mask (swapped layout: key index in-regs)
            #pragma unroll
            for (int nt = 0; nt < 4; ++nt)
                #pragma unroll
                for (int r = 0; r < 4; ++r) {
                    int kg = jt*64 + nt*16 + quad*4 + r;
                    int qg = rhi + lr;
                    if (kg > qg) SaH[nt][r] = -INFINITY;
                }
        }
        if (jt == qlo) {
            #pragma unroll
            for (int nt = 0; nt < 4; ++nt)
                #pragma unroll
                for (int r = 0; r < 4; ++r) {
                    int kg = jt*64 + nt*16 + quad*4 + r;
                    int qg = rlo + lr;
                    if (kg > qg) SaL[nt][r] = -INFINITY;
                }
        }

        // P = exp2(S); scalar row-sum; packed b64 writes (compiler emits
        // v_cvt_pk_bf16_f32 from the paired casts — NO inline asm).
        #pragma unroll
        for (int nt = 0; nt < 4; ++nt) {
            float e0 = __builtin_amdgcn_exp2f(SaH[nt][0]);
            float e1 = __builtin_amdgcn_exp2f(SaH[nt][1]);
            float e2 = __builtin_amdgcn_exp2f(SaH[nt][2]);
            float e3 = __builtin_amdgcn_exp2f(SaH[nt][3]);
            lsumH += (e0 + e1) + (e2 + e3);
            ushort4 w;
            w.x = f2bf(e0); w.y = f2bf(e1); w.z = f2bf(e2); w.w = f2bf(e3);
            *reinterpret_cast<ushort4*>(PsH + off64[nt]) = w;
        }
        if (lo) {
            #pragma unroll
            for (int nt = 0; nt < 4; ++nt) {
                float e0 = __builtin_amdgcn_exp2f(SaL[nt][0]);
                float e1 = __builtin_amdgcn_exp2f(SaL[nt][1]);
                float e2 = __builtin_amdgcn_exp2f(SaL[nt][2]);
                float e3 = __builtin_amdgcn_exp2f(SaL[nt][3]);
                lsumL += (e0 + e1) + (e2 + e3);
                ushort4 w;
                w.x = f2bf(e0); w.y = f2bf(e1); w.z = f2bf(e2); w.w = f2bf(e3);
                *reinterpret_cast<ushort4*>(PsL + off64[nt]) = w;
            }
        }

        // O += P @ V: shared V fragments feed both q-sets.
        // (same-wave LDS write->read ordering via lgkmcnt; no barrier)
        __builtin_amdgcn_s_setprio(1);
        #pragma unroll
        for (int kk = 0; kk < 2; ++kk) {
            int rb = kk ? rb1 : rb0;
            bf16x8 paH = *reinterpret_cast<const bf16x8*>(PsH + rb);
            bf16x8 paL = *reinterpret_cast<const bf16x8*>(PsL + rb);
            #pragma unroll
            for (int nt = 0; nt < 4; ++nt) {
                bf16x8 vb = *reinterpret_cast<const bf16x8*>(Vs + rb + nt*1024);
                OaH[nt] = __builtin_amdgcn_mfma_f32_16x16x32_bf16(paH, vb, OaH[nt], 0, 0, 0);
                if (lo)
                    OaL[nt] = __builtin_amdgcn_mfma_f32_16x16x32_bf16(paL, vb, OaL[nt], 0, 0, 0);
            }
        }
        __builtin_amdgcn_s_setprio(0);
    }

    // epilogue: full row sums (reduce across quads), normalize, store.
    // lsum holds q=lr's partial; O rows are q=quad*4+r -> broadcast via shfl.
    int b = bh >> 4, h = bh & 15;
    float sH = lsumH;
    sH += __shfl_xor(sH, 16, 64);
    sH += __shfl_xor(sH, 32, 64);
    float sL = lsumL;
    sL += __shfl_xor(sL, 16, 64);
    sL += __shfl_xor(sL, 32, 64);
    #pragma unroll
    for (int r = 0; r < 4; ++r) {
        float invH = 1.f / __shfl(sH, quad*4 + r, 64);
        float invL = 1.f / __shfl(sL, quad*4 + r, 64);
        int qgH = rhi + quad*4 + r;
        int qgL = rlo + quad*4 + r;
        #pragma unroll
        for (int nt = 0; nt < 4; ++nt) {
            int d = nt*16 + lr;
            Ob[((size_t)b*T_ + qgH)*D_ + h*HS_ + d] = f2bf(OaH[nt][r] * invH);
            Ob[((size_t)b*T_ + qgL)*D_ + h*HS_ + d] = f2bf(OaL[nt][r] * invL);
        }
    }
}

extern "C" void kernel_launch(void* const* d_in, const int* in_sizes, int n_in,
                              void* d_out, int out_size, void* d_ws, size_t ws_size,
                              hipStream_t stream) {
    (void)in_sizes; (void)n_in; (void)out_size; (void)ws_size;
    const float* x     = (const float*)d_in[0];
    const float* w_qkv = (const float*)d_in[1];
    const float* b_qkv = (const float*)d_in[2];
    const float* w_out = (const float*)d_in[3];
    const float* b_out = (const float*)d_in[4];
    float* out = (float*)d_out;

    char* ws = (char*)d_ws;
    u16* Xb    = (u16*)ws; ws += (size_t)M_ * D_ * 2;
    u16* WqkvT = (u16*)ws; ws += (size_t)3 * D_ * D_ * 2;
    u16* WoutT = (u16*)ws; ws += (size_t)D_ * D_ * 2;
    u16* Qb    = (u16*)ws; ws += (size_t)M_ * D_ * 2;
    u16* Kb    = (u16*)ws; ws += (size_t)M_ * D_ * 2;
    u16* Vt    = (u16*)ws; ws += (size_t)M_ * D_ * 2;
    u16* Ob    = (u16*)ws; ws += (size_t)M_ * D_ * 2;

    prep_kernel<<<8192, 256, 0, stream>>>(x, w_qkv, w_out, Xb, WqkvT, WoutT);
    gemm_qkv<<<dim3(16, 12), 512, 0, stream>>>(
        Xb, WqkvT, b_qkv, Qb, Kb, Vt);
    // paired q-tiles, swapped-QK in-register-row softmax: 512 blocks
    attn_kernel<<<512, 256, 0, stream>>>(Qb, Kb, Vt, Ob);
    gemm_out<<<dim3(M_/128, D_/128), 256, 0, stream>>>(Ob, WoutT, b_out, out);
}